// Round 5
// baseline (1705.452 us; speedup 1.0000x reference)
//
#include <hip/hip_runtime.h>
#include <hip/hip_fp16.h>

#define D 48
#define W 3
#define NX 160
#define NY 160
#define NZ 160
#define NPTS (NX*NY*NZ)        // 4,096,000
#define KNBR 8
#define EPSV 1e-5f
#define NTV (159*159*159)      // 4,019,679
#define NBTV 2048              // TV partial blocks
#define TVROWS (159*159)
#define CPAIRS 80
#define TVSLOTS (TVROWS*CPAIRS)   // 2,022,480

#define SLICES 16
#define SLICE_SHIFT 18         // 2^18 entries * 8 B = 2 MB window (fits 4 MiB XCD L2)
#define PPT 4                  // points per thread (regs: 32 ids + 32 w + 12 acc)

typedef int   vint4   __attribute__((ext_vector_type(4)));
typedef float vfloat4 __attribute__((ext_vector_type(4)));

// workspace layout (float offsets)
#define T1_OFF 0
#define T1_SZ (W*NX*D*D)              // 1,105,920 floats
#define TVP_OFF (T1_OFF + T1_SZ)
#define G3_OFF (TVP_OFF + NBTV)       // 16B-aligned
// g3h: NPTS entries of 8 bytes (half4: g0,g1,g2,pad) as uint2

__device__ inline void unpack3(uint2 u, float& f0, float& f1, float& f2) {
    __half2 lo = *reinterpret_cast<__half2*>(&u.x);
    __half2 hi = *reinterpret_cast<__half2*>(&u.y);
    f0 = __low2float(lo);
    f1 = __high2float(lo);
    f2 = __low2float(hi);
}

// ---------------------------------------------------------------------------
// k1: t1[w][a][q][r] = sum_p x[a][p] * wt[w][p][q][r]
__global__ __launch_bounds__(256) void k1(const float* __restrict__ x,
                                          const float* __restrict__ wt,
                                          float* __restrict__ t1) {
    int lane = threadIdx.x & 63;
    int wv   = threadIdx.x >> 6;
    int q    = blockIdx.x * 4 + wv;
    int a0   = blockIdx.y * 16;
    int w    = blockIdx.z;
    bool act = lane < D;

    float wreg[D];
#pragma unroll
    for (int p = 0; p < D; ++p)
        wreg[p] = act ? wt[((w*D + p)*D + q)*D + lane] : 0.f;

    for (int ai = 0; ai < 16; ++ai) {
        int a = a0 + ai;
        const float4* xp = (const float4*)(x + a*D);
        float s = 0.f;
#pragma unroll
        for (int j = 0; j < D/4; ++j) {
            float4 xv = xp[j];
            s += xv.x * wreg[4*j+0];
            s += xv.y * wreg[4*j+1];
            s += xv.z * wreg[4*j+2];
            s += xv.w * wreg[4*j+3];
        }
        if (act) t1[((w*NX + a)*D + q)*D + lane] = s;
    }
}

// ---------------------------------------------------------------------------
// kbcd: fused k2+k3 for one (a, b-half). t1 slice -> LDS, t2 -> LDS, pack g3h.
#define BH 80
__global__ __launch_bounds__(192) void kbcd(const float* __restrict__ y,
                                            const float* __restrict__ z,
                                            const float* __restrict__ t1,
                                            uint2* __restrict__ g3h) {
    __shared__ float t1s[W*D*D];     // [w][q][r], 27.6 KB
    __shared__ float t2s[W*BH*D];    // [w][bh][r], 46.1 KB
    int tid = threadIdx.x;
    int a   = blockIdx.y;
    int b0  = blockIdx.x * BH;

    int c = tid;
    bool act = c < NZ;
    float zreg[D];
#pragma unroll
    for (int j = 0; j < D/4; ++j) {
        float4 zv = act ? ((const float4*)(z + c*D))[j] : make_float4(0,0,0,0);
        zreg[4*j+0] = zv.x; zreg[4*j+1] = zv.y; zreg[4*j+2] = zv.z; zreg[4*j+3] = zv.w;
    }

    for (int i = tid; i < W*D*D; i += 192) {
        int w = i / (D*D), rem = i - w*(D*D);
        t1s[i] = t1[(size_t)(w*NX + a)*(D*D) + rem];
    }
    __syncthreads();

    for (int i = tid; i < W*BH*(D/4); i += 192) {
        int w   = i / (BH*(D/4));
        int rem = i - w*(BH*(D/4));
        int bh  = rem / (D/4);
        int r4  = rem - bh*(D/4);
        const float4* yb  = (const float4*)(y + (b0 + bh)*D);
        const float4* t1v = (const float4*)(t1s + w*D*D) + r4;
        float4 s = make_float4(0,0,0,0);
#pragma unroll
        for (int q4 = 0; q4 < D/4; ++q4) {
            float4 yv = yb[q4];
#pragma unroll
            for (int u = 0; u < 4; ++u) {
                float yq = (u==0) ? yv.x : (u==1) ? yv.y : (u==2) ? yv.z : yv.w;
                float4 tv = t1v[(q4*4+u)*(D/4)];
                s.x += yq*tv.x; s.y += yq*tv.y; s.z += yq*tv.z; s.w += yq*tv.w;
            }
        }
        ((float4*)t2s)[i] = s;
    }
    __syncthreads();

    for (int bh = 0; bh < BH; ++bh) {
        float acc[W];
#pragma unroll
        for (int w = 0; w < W; ++w) {
            const float4* t2v = (const float4*)(t2s + (w*BH + bh)*D);
            float s = 0.f;
#pragma unroll
            for (int j = 0; j < D/4; ++j) {
                float4 t = t2v[j];
                s += t.x*zreg[4*j+0] + t.y*zreg[4*j+1] + t.z*zreg[4*j+2] + t.w*zreg[4*j+3];
            }
            acc[w] = s;
        }
        if (act) {
            __half2 lo = __halves2half2(__float2half_rn(acc[0]), __float2half_rn(acc[1]));
            __half2 hi = __halves2half2(__float2half_rn(acc[2]), __float2half_rn(0.f));
            uint2 u;
            u.x = *reinterpret_cast<unsigned*>(&lo);
            u.y = *reinterpret_cast<unsigned*>(&hi);
            g3h[(size_t)((a*NY + (b0+bh))*NZ + c)] = u;
        }
    }
}

// ---------------------------------------------------------------------------
__device__ inline float tv3(uint2 u0, uint2 uc, uint2 ub, uint2 ua) {
    float b0,b1,b2, c0,c1,c2, d0,d1,d2, e0,e1,e2;
    unpack3(u0,b0,b1,b2); unpack3(uc,c0,c1,c2);
    unpack3(ub,d0,d1,d2); unpack3(ua,e0,e1,e2);
    float x0=c0-b0, y0=d0-b0, z0=e0-b0;
    float x1=c1-b1, y1=d1-b1, z1=e1-b1;
    float x2=c2-b2, y2=d2-b2, z2=e2-b2;
    return sqrtf(EPSV + x0*x0 + y0*y0 + z0*z0)
         + sqrtf(EPSV + x1*x1 + y1*y1 + z1*z1)
         + sqrtf(EPSV + x2*x2 + y2*y2 + z2*z2);
}

__global__ __launch_bounds__(256) void ktv(const uint2* __restrict__ g3h,
                                           float* __restrict__ partial) {
    float v = 0.f;
    for (int s = blockIdx.x * 256 + threadIdx.x; s < TVSLOTS; s += NBTV * 256) {
        int c2  = s % CPAIRS;
        int row = s / CPAIRS;
        int b   = row % 159;
        int a   = row / 159;
        int c   = 2*c2;
        size_t p = (size_t)(a*NY + b)*NZ + c;
        uint4 u0 = *(const uint4*)(g3h + p);
        uint4 ub = *(const uint4*)(g3h + p + NZ);
        uint4 ua = *(const uint4*)(g3h + p + NY*NZ);
        uint2 un = g3h[p + 2];
        uint2 u0l = make_uint2(u0.x, u0.y), u0h = make_uint2(u0.z, u0.w);
        uint2 ubl = make_uint2(ub.x, ub.y), ubh = make_uint2(ub.z, ub.w);
        uint2 ual = make_uint2(ua.x, ua.y), uah = make_uint2(ua.z, ua.w);
        v += tv3(u0l, u0h, ubl, ual);
        if (c + 1 < 159)
            v += tv3(u0h, un, ubh, uah);
    }
#pragma unroll
    for (int off = 32; off > 0; off >>= 1)
        v += __shfl_down(v, off, 64);
    __shared__ float sred[4];
    int lane = threadIdx.x & 63, wv = threadIdx.x >> 6;
    if (lane == 0) sred[wv] = v;
    __syncthreads();
    if (threadIdx.x == 0)
        partial[blockIdx.x] = sred[0] + sred[1] + sred[2] + sred[3];
}

__global__ __launch_bounds__(256) void kred(const float* __restrict__ partial,
                                            float* __restrict__ outreg) {
    float v = 0.f;
    for (int i = threadIdx.x; i < NBTV; i += 256) v += partial[i];
#pragma unroll
    for (int off = 32; off > 0; off >>= 1)
        v += __shfl_down(v, off, 64);
    __shared__ float sred[4];
    int lane = threadIdx.x & 63, wv = threadIdx.x >> 6;
    if (lane == 0) sred[wv] = v;
    __syncthreads();
    if (threadIdx.x == 0)
        outreg[0] = (sred[0] + sred[1] + sred[2] + sred[3]) * (1.0f / (float)NTV);
}

// ---------------------------------------------------------------------------
// slice-phased gather: PPT points/thread, 16 phases over 2 MB table windows.
__global__ __launch_bounds__(256) void kgather(const int* __restrict__ bidx,
                                               const float* __restrict__ bw,
                                               const uint2* __restrict__ g3h,
                                               float* __restrict__ out,
                                               int np) {
    int gid = blockIdx.x * 256 + threadIdx.x;
    int nth = np / PPT;            // 500,000 threads
    if (gid >= nth) return;

    const vint4*   ip = (const vint4*)bidx;
    const vfloat4* wp = (const vfloat4*)bw;

    int   ids[PPT*KNBR];
    float wws[PPT*KNBR];
#pragma unroll
    for (int t = 0; t < PPT; ++t) {
        size_t n = (size_t)gid + (size_t)t * nth;
        vint4   i0 = __builtin_nontemporal_load(ip + n*2);
        vint4   i1 = __builtin_nontemporal_load(ip + n*2 + 1);
        vfloat4 w0 = __builtin_nontemporal_load(wp + n*2);
        vfloat4 w1 = __builtin_nontemporal_load(wp + n*2 + 1);
        ids[t*KNBR+0]=i0.x; ids[t*KNBR+1]=i0.y; ids[t*KNBR+2]=i0.z; ids[t*KNBR+3]=i0.w;
        ids[t*KNBR+4]=i1.x; ids[t*KNBR+5]=i1.y; ids[t*KNBR+6]=i1.z; ids[t*KNBR+7]=i1.w;
        wws[t*KNBR+0]=w0.x; wws[t*KNBR+1]=w0.y; wws[t*KNBR+2]=w0.z; wws[t*KNBR+3]=w0.w;
        wws[t*KNBR+4]=w1.x; wws[t*KNBR+5]=w1.y; wws[t*KNBR+6]=w1.z; wws[t*KNBR+7]=w1.w;
    }

    float acc[PPT][3];
#pragma unroll
    for (int t = 0; t < PPT; ++t) { acc[t][0]=0.f; acc[t][1]=0.f; acc[t][2]=0.f; }

    for (int s = 0; s < SLICES; ++s) {     // runtime loop: blocks sweep windows
#pragma unroll
        for (int t = 0; t < PPT; ++t) {
#pragma unroll
            for (int k = 0; k < KNBR; ++k) {
                int id = ids[t*KNBR+k];
                if ((id >> SLICE_SHIFT) == s) {
                    uint2 u = g3h[(size_t)id];
                    float f0,f1,f2;
                    unpack3(u, f0,f1,f2);
                    float wk = wws[t*KNBR+k];
                    acc[t][0] += f0*wk;
                    acc[t][1] += f1*wk;
                    acc[t][2] += f2*wk;
                }
            }
        }
        __syncthreads();   // keep block's waves phase-aligned
    }

#pragma unroll
    for (int t = 0; t < PPT; ++t) {
        float* op = out + ((size_t)gid + (size_t)t * nth) * 3;
        __builtin_nontemporal_store(acc[t][0], op+0);
        __builtin_nontemporal_store(acc[t][1], op+1);
        __builtin_nontemporal_store(acc[t][2], op+2);
    }
}

// ---------------------------------------------------------------------------
extern "C" void kernel_launch(void* const* d_in, const int* in_sizes, int n_in,
                              void* d_out, int out_size, void* d_ws, size_t ws_size,
                              hipStream_t stream) {
    const float* x    = (const float*)d_in[0];
    const float* y    = (const float*)d_in[1];
    const float* z    = (const float*)d_in[2];
    const float* wt   = (const float*)d_in[3];
    const int*   bidx = (const int*)d_in[4];
    const float* bw   = (const float*)d_in[5];
    float* out = (float*)d_out;
    float* ws  = (float*)d_ws;

    float* t1  = ws + T1_OFF;
    float* tvp = ws + TVP_OFF;
    uint2* g3h = (uint2*)(ws + G3_OFF);
    int np = in_sizes[4] / KNBR;   // 2,000,000

    k1  <<<dim3(12, 10, 3), 256, 0, stream>>>(x, wt, t1);
    kbcd<<<dim3(2, NX),     192, 0, stream>>>(y, z, t1, g3h);

    ktv <<<dim3(NBTV), 256, 0, stream>>>(g3h, tvp);
    kred<<<dim3(1),    256, 0, stream>>>(tvp, out + (out_size - 1));

    int nth = np / PPT;
    kgather<<<dim3((nth + 255) / 256), 256, 0, stream>>>(bidx, bw, g3h, out, np);
}

// Round 6
// 526.219 us; speedup vs baseline: 3.2410x; 3.2410x over previous
//
#include <hip/hip_runtime.h>
#include <hip/hip_fp16.h>

#define D 48
#define W 3
#define NX 160
#define NY 160
#define NZ 160
#define NPTS (NX*NY*NZ)        // 4,096,000
#define KNBR 8
#define EPSV 1e-5f
#define NTV (159*159*159)      // 4,019,679
#define TVROWS (159*159)
#define CPAIRS 80
#define TVSLOTS (TVROWS*CPAIRS)   // 2,022,480

typedef int   vint4   __attribute__((ext_vector_type(4)));
typedef float vfloat4 __attribute__((ext_vector_type(4)));

// workspace layout (float offsets)
#define T1_OFF 0
#define T1_SZ (W*NX*D*D)              // 1,105,920 floats
#define TVP_OFF (T1_OFF + T1_SZ)
#define TVP_SZ 4096                   // >= grid of kgtv (3907)
#define G3_OFF (TVP_OFF + TVP_SZ)     // 1,110,016 floats -> 4,440,064 B (16B aligned)
// g3h: NPTS entries of 8 bytes (half4: g0,g1,g2,pad) as uint2

__device__ inline void unpack3(uint2 u, float& f0, float& f1, float& f2) {
    __half2 lo = *reinterpret_cast<__half2*>(&u.x);
    __half2 hi = *reinterpret_cast<__half2*>(&u.y);
    f0 = __low2float(lo);
    f1 = __high2float(lo);
    f2 = __low2float(hi);
}

// ---------------------------------------------------------------------------
// k1: t1[w][a][q][r] = sum_p x[a][p] * wt[w][p][q][r]
__global__ __launch_bounds__(256) void k1(const float* __restrict__ x,
                                          const float* __restrict__ wt,
                                          float* __restrict__ t1) {
    int lane = threadIdx.x & 63;
    int wv   = threadIdx.x >> 6;
    int q    = blockIdx.x * 4 + wv;
    int a0   = blockIdx.y * 16;
    int w    = blockIdx.z;
    bool act = lane < D;

    float wreg[D];
#pragma unroll
    for (int p = 0; p < D; ++p)
        wreg[p] = act ? wt[((w*D + p)*D + q)*D + lane] : 0.f;

    for (int ai = 0; ai < 16; ++ai) {
        int a = a0 + ai;
        const float4* xp = (const float4*)(x + a*D);
        float s = 0.f;
#pragma unroll
        for (int j = 0; j < D/4; ++j) {
            float4 xv = xp[j];
            s += xv.x * wreg[4*j+0];
            s += xv.y * wreg[4*j+1];
            s += xv.z * wreg[4*j+2];
            s += xv.w * wreg[4*j+3];
        }
        if (act) t1[((w*NX + a)*D + q)*D + lane] = s;
    }
}

// ---------------------------------------------------------------------------
// kbcd: fused k2+k3 for one (a, b-half). t1 slice -> LDS, t2 -> LDS, pack g3h.
#define BH 80
__global__ __launch_bounds__(192) void kbcd(const float* __restrict__ y,
                                            const float* __restrict__ z,
                                            const float* __restrict__ t1,
                                            uint2* __restrict__ g3h) {
    __shared__ float t1s[W*D*D];     // [w][q][r], 27.6 KB
    __shared__ float t2s[W*BH*D];    // [w][bh][r], 46.1 KB
    int tid = threadIdx.x;
    int a   = blockIdx.y;
    int b0  = blockIdx.x * BH;

    int c = tid;
    bool act = c < NZ;
    float zreg[D];
#pragma unroll
    for (int j = 0; j < D/4; ++j) {
        float4 zv = act ? ((const float4*)(z + c*D))[j] : make_float4(0,0,0,0);
        zreg[4*j+0] = zv.x; zreg[4*j+1] = zv.y; zreg[4*j+2] = zv.z; zreg[4*j+3] = zv.w;
    }

    for (int i = tid; i < W*D*D; i += 192) {
        int w = i / (D*D), rem = i - w*(D*D);
        t1s[i] = t1[(size_t)(w*NX + a)*(D*D) + rem];
    }
    __syncthreads();

    for (int i = tid; i < W*BH*(D/4); i += 192) {
        int w   = i / (BH*(D/4));
        int rem = i - w*(BH*(D/4));
        int bh  = rem / (D/4);
        int r4  = rem - bh*(D/4);
        const float4* yb  = (const float4*)(y + (b0 + bh)*D);
        const float4* t1v = (const float4*)(t1s + w*D*D) + r4;
        float4 s = make_float4(0,0,0,0);
#pragma unroll
        for (int q4 = 0; q4 < D/4; ++q4) {
            float4 yv = yb[q4];
#pragma unroll
            for (int u = 0; u < 4; ++u) {
                float yq = (u==0) ? yv.x : (u==1) ? yv.y : (u==2) ? yv.z : yv.w;
                float4 tv = t1v[(q4*4+u)*(D/4)];
                s.x += yq*tv.x; s.y += yq*tv.y; s.z += yq*tv.z; s.w += yq*tv.w;
            }
        }
        ((float4*)t2s)[i] = s;
    }
    __syncthreads();

    for (int bh = 0; bh < BH; ++bh) {
        float acc[W];
#pragma unroll
        for (int w = 0; w < W; ++w) {
            const float4* t2v = (const float4*)(t2s + (w*BH + bh)*D);
            float s = 0.f;
#pragma unroll
            for (int j = 0; j < D/4; ++j) {
                float4 t = t2v[j];
                s += t.x*zreg[4*j+0] + t.y*zreg[4*j+1] + t.z*zreg[4*j+2] + t.w*zreg[4*j+3];
            }
            acc[w] = s;
        }
        if (act) {
            __half2 lo = __halves2half2(__float2half_rn(acc[0]), __float2half_rn(acc[1]));
            __half2 hi = __halves2half2(__float2half_rn(acc[2]), __float2half_rn(0.f));
            uint2 u;
            u.x = *reinterpret_cast<unsigned*>(&lo);
            u.y = *reinterpret_cast<unsigned*>(&hi);
            g3h[(size_t)((a*NY + (b0+bh))*NZ + c)] = u;
        }
    }
}

// ---------------------------------------------------------------------------
__device__ inline float tv3(uint2 u0, uint2 uc, uint2 ub, uint2 ua) {
    float b0,b1,b2, c0,c1,c2, d0,d1,d2, e0,e1,e2;
    unpack3(u0,b0,b1,b2); unpack3(uc,c0,c1,c2);
    unpack3(ub,d0,d1,d2); unpack3(ua,e0,e1,e2);
    float x0=c0-b0, y0=d0-b0, z0=e0-b0;
    float x1=c1-b1, y1=d1-b1, z1=e1-b1;
    float x2=c2-b2, y2=d2-b2, z2=e2-b2;
    return sqrtf(EPSV + x0*x0 + y0*y0 + z0*z0)
         + sqrtf(EPSV + x1*x1 + y1*y1 + z1*z1)
         + sqrtf(EPSV + x2*x2 + y2*y2 + z2*z2);
}

// ---------------------------------------------------------------------------
// kgtv: fused TV (grid-stride prologue, block partial) + gather (R4 shape:
// 2 points per thread, 16 random loads in flight). TV's streaming loads
// overlap the gather's latency-bound random loads at wave level.
__global__ __launch_bounds__(256) void kgtv(const int* __restrict__ bidx,
                                            const float* __restrict__ bw,
                                            const uint2* __restrict__ g3h,
                                            float* __restrict__ out,
                                            float* __restrict__ partial,
                                            int np) {
    int gid  = blockIdx.x * 256 + threadIdx.x;
    int half = np >> 1;
    int gsz  = gridDim.x * 256;

    // ---- gather stream loads (issue early; consumed after TV) ----
    bool gact = gid < half;
    int n1 = gact ? gid : 0;
    int n2 = n1 + (gact ? half : 0);
    const vint4*   ip = (const vint4*)bidx;
    const vfloat4* wp = (const vfloat4*)bw;
    vint4   i0 = __builtin_nontemporal_load(ip + (size_t)n1*2);
    vint4   i1 = __builtin_nontemporal_load(ip + (size_t)n1*2 + 1);
    vint4   j0 = __builtin_nontemporal_load(ip + (size_t)n2*2);
    vint4   j1 = __builtin_nontemporal_load(ip + (size_t)n2*2 + 1);
    vfloat4 w0 = __builtin_nontemporal_load(wp + (size_t)n1*2);
    vfloat4 w1 = __builtin_nontemporal_load(wp + (size_t)n1*2 + 1);
    vfloat4 v0 = __builtin_nontemporal_load(wp + (size_t)n2*2);
    vfloat4 v1 = __builtin_nontemporal_load(wp + (size_t)n2*2 + 1);

    // ---- TV prologue: grid-stride over c-pair slots ----
    float v = 0.f;
    for (int s = gid; s < TVSLOTS; s += gsz) {
        int c2  = s % CPAIRS;
        int row = s / CPAIRS;
        int b   = row % 159;
        int a   = row / 159;
        int c   = 2*c2;
        size_t p = (size_t)(a*NY + b)*NZ + c;
        uint4 u0 = *(const uint4*)(g3h + p);
        uint4 ub = *(const uint4*)(g3h + p + NZ);
        uint4 ua = *(const uint4*)(g3h + p + NY*NZ);
        uint2 un = g3h[p + 2];
        uint2 u0l = make_uint2(u0.x, u0.y), u0h = make_uint2(u0.z, u0.w);
        uint2 ubl = make_uint2(ub.x, ub.y), ubh = make_uint2(ub.z, ub.w);
        uint2 ual = make_uint2(ua.x, ua.y), uah = make_uint2(ua.z, ua.w);
        v += tv3(u0l, u0h, ubl, ual);
        if (c + 1 < 159)
            v += tv3(u0h, un, ubh, uah);
    }
#pragma unroll
    for (int off = 32; off > 0; off >>= 1)
        v += __shfl_down(v, off, 64);
    __shared__ float sred[4];
    int lane = threadIdx.x & 63, wv = threadIdx.x >> 6;
    if (lane == 0) sred[wv] = v;
    __syncthreads();
    if (threadIdx.x == 0)
        partial[blockIdx.x] = sred[0] + sred[1] + sred[2] + sred[3];

    // ---- gather body ----
    if (!gact) return;
    int   idsA[KNBR] = {i0.x, i0.y, i0.z, i0.w, i1.x, i1.y, i1.z, i1.w};
    int   idsB[KNBR] = {j0.x, j0.y, j0.z, j0.w, j1.x, j1.y, j1.z, j1.w};
    float wwsA[KNBR] = {w0.x, w0.y, w0.z, w0.w, w1.x, w1.y, w1.z, w1.w};
    float wwsB[KNBR] = {v0.x, v0.y, v0.z, v0.w, v1.x, v1.y, v1.z, v1.w};

    uint2 uA[KNBR], uB[KNBR];
#pragma unroll
    for (int k = 0; k < KNBR; ++k) uA[k] = g3h[(size_t)idsA[k]];
#pragma unroll
    for (int k = 0; k < KNBR; ++k) uB[k] = g3h[(size_t)idsB[k]];

    float a0=0.f, a1=0.f, a2=0.f, b0=0.f, b1=0.f, b2=0.f;
#pragma unroll
    for (int k = 0; k < KNBR; ++k) {
        float f0,f1,f2;
        unpack3(uA[k], f0,f1,f2);
        a0 += f0*wwsA[k]; a1 += f1*wwsA[k]; a2 += f2*wwsA[k];
    }
#pragma unroll
    for (int k = 0; k < KNBR; ++k) {
        float f0,f1,f2;
        unpack3(uB[k], f0,f1,f2);
        b0 += f0*wwsB[k]; b1 += f1*wwsB[k]; b2 += f2*wwsB[k];
    }
    float* opA = out + (size_t)n1*3;
    float* opB = out + (size_t)n2*3;
    __builtin_nontemporal_store(a0, opA+0);
    __builtin_nontemporal_store(a1, opA+1);
    __builtin_nontemporal_store(a2, opA+2);
    __builtin_nontemporal_store(b0, opB+0);
    __builtin_nontemporal_store(b1, opB+1);
    __builtin_nontemporal_store(b2, opB+2);
}

// final reduce of nb partials -> scalar (mean)
__global__ __launch_bounds__(256) void kred(const float* __restrict__ partial,
                                            float* __restrict__ outreg, int nb) {
    float v = 0.f;
    for (int i = threadIdx.x; i < nb; i += 256) v += partial[i];
#pragma unroll
    for (int off = 32; off > 0; off >>= 1)
        v += __shfl_down(v, off, 64);
    __shared__ float sred[4];
    int lane = threadIdx.x & 63, wv = threadIdx.x >> 6;
    if (lane == 0) sred[wv] = v;
    __syncthreads();
    if (threadIdx.x == 0)
        outreg[0] = (sred[0] + sred[1] + sred[2] + sred[3]) * (1.0f / (float)NTV);
}

// ---------------------------------------------------------------------------
extern "C" void kernel_launch(void* const* d_in, const int* in_sizes, int n_in,
                              void* d_out, int out_size, void* d_ws, size_t ws_size,
                              hipStream_t stream) {
    const float* x    = (const float*)d_in[0];
    const float* y    = (const float*)d_in[1];
    const float* z    = (const float*)d_in[2];
    const float* wt   = (const float*)d_in[3];
    const int*   bidx = (const int*)d_in[4];
    const float* bw   = (const float*)d_in[5];
    float* out = (float*)d_out;
    float* ws  = (float*)d_ws;

    float* t1  = ws + T1_OFF;
    float* tvp = ws + TVP_OFF;
    uint2* g3h = (uint2*)(ws + G3_OFF);
    int np = in_sizes[4] / KNBR;   // 2,000,000

    k1  <<<dim3(12, 10, 3), 256, 0, stream>>>(x, wt, t1);
    kbcd<<<dim3(2, NX),     192, 0, stream>>>(y, z, t1, g3h);

    int nb = (np/2 + 255) / 256;   // 3907
    kgtv<<<dim3(nb), 256, 0, stream>>>(bidx, bw, g3h, out, tvp, np);
    kred<<<dim3(1),  256, 0, stream>>>(tvp, out + (out_size - 1), nb);
}